// Round 1
// baseline (439.879 us; speedup 1.0000x reference)
//
#include <hip/hip_runtime.h>

typedef __bf16 bf16;
typedef bf16 bf16x8 __attribute__((ext_vector_type(8)));
typedef float floatx4 __attribute__((ext_vector_type(4)));

#define AS1 __attribute__((address_space(1)))
#define AS3 __attribute__((address_space(3)))

// ---------------------------------------------------------------------------
// Core tile machinery: 128x128 block, 4 waves (2x2 of 64x64), BK=64,
// 16x16x32 bf16 MFMA. Both operands stored [row][k] (k-contiguous).
// Staging: global_load_lds width=16, lane-contiguous LDS, XOR swizzle applied
// to the GLOBAL column so ds_read_b128 fragment loads are conflict-free.
// LDS[row][c8] = G[row][c8 ^ (row&7)], tile = 128 rows x 64 k (16 KB).
// ---------------------------------------------------------------------------
__device__ __forceinline__ void stage_tile(const bf16* g, int ld, bf16* lds, int tid) {
#pragma unroll
    for (int it = 0; it < 4; ++it) {
        int q    = it * 256 + tid;        // 0..1023, 8 bf16 per q
        int row  = q >> 3;
        int col8 = (q & 7) ^ (row & 7);   // swizzle on global side
        __builtin_amdgcn_global_load_lds(
            (const AS1 void*)(g + (size_t)row * ld + col8 * 8),
            (AS3 void*)(lds + q * 8), 16, 0, 0);
    }
}

__device__ __forceinline__ void mfma_block(const bf16* lA, const bf16* lB,
                                           floatx4 acc[4][4], int lane, int wm, int wn) {
    const int lrow = lane & 15;
    const int lk   = lane >> 4;
#pragma unroll
    for (int s = 0; s < 2; ++s) {   // two K=32 steps per BK=64
        bf16x8 af[4], bfr[4];
        const int c8 = s * 4 + lk;
#pragma unroll
        for (int mi = 0; mi < 4; ++mi) {
            int r = wm * 64 + mi * 16 + lrow;
            af[mi] = *(const bf16x8*)(lA + r * 64 + ((c8 ^ (r & 7)) << 3));
        }
#pragma unroll
        for (int ni = 0; ni < 4; ++ni) {
            int r = wn * 64 + ni * 16 + lrow;
            bfr[ni] = *(const bf16x8*)(lB + r * 64 + ((c8 ^ (r & 7)) << 3));
        }
#pragma unroll
        for (int mi = 0; mi < 4; ++mi)
#pragma unroll
            for (int ni = 0; ni < 4; ++ni)
                acc[mi][ni] = __builtin_amdgcn_mfma_f32_16x16x32_bf16(
                    af[mi], bfr[ni], acc[mi][ni], 0, 0, 0);
    }
}

// ---------------------------------------------------------------------------
// GEMM1: YT[kv*512+o][t] = sum_d WbT[kv*512+o][d] * xb[t][d]
//   A = WbT (24576 x 512), B = xb (2048 x 512), both [row][k]. Grid (192,16).
// ---------------------------------------------------------------------------
__global__ __launch_bounds__(256) void yt_gemm(const bf16* __restrict__ WbT,
                                               const bf16* __restrict__ xb,
                                               bf16* __restrict__ YT) {
    __shared__ bf16 lA[128 * 64], lB[128 * 64];
    const int tid = threadIdx.x;
    const int lane = tid & 63, wave = tid >> 6, wm = wave & 1, wn = wave >> 1;
    const int bm = blockIdx.x, bn = blockIdx.y;
    const bf16* Ab = WbT + (size_t)bm * 128 * 512;
    const bf16* Bb = xb + (size_t)bn * 128 * 512;

    floatx4 acc[4][4];
    floatx4 zero = {0.f, 0.f, 0.f, 0.f};
#pragma unroll
    for (int mi = 0; mi < 4; ++mi)
#pragma unroll
        for (int ni = 0; ni < 4; ++ni) acc[mi][ni] = zero;

    for (int kk = 0; kk < 512; kk += 64) {
        stage_tile(Ab + kk, 512, lA, tid);
        stage_tile(Bb + kk, 512, lB, tid);
        __syncthreads();
        mfma_block(lA, lB, acc, lane, wm, wn);
        __syncthreads();
    }
    // D row = A-row (ko), D col = B-row (t); C/D: col=lane&15, row=(lane>>4)*4+r
#pragma unroll
    for (int mi = 0; mi < 4; ++mi)
#pragma unroll
        for (int ni = 0; ni < 4; ++ni)
#pragma unroll
            for (int r = 0; r < 4; ++r) {
                int ko = bm * 128 + wm * 64 + mi * 16 + (lane >> 4) * 4 + r;
                int t  = bn * 128 + wn * 64 + ni * 16 + (lane & 15);
                YT[(size_t)ko * 2048 + t] = (bf16)acc[mi][ni][r];
            }
}

// ---------------------------------------------------------------------------
// conv GEMM: one block per (p=(a,c) pair, n). K = 48 slices x 128.
//   A = Tb[kv][a-c] (128x128, [i][j]), B = YT slice rows o ([o][s]).
//   Writes packed partial tile P[(p*4+n)] (128x128 fp32).
// ---------------------------------------------------------------------------
__global__ __launch_bounds__(256) void conv_gemm(const bf16* __restrict__ Tb,
                                                 const bf16* __restrict__ YT,
                                                 float* __restrict__ P) {
    __shared__ bf16 lA[128 * 64], lB[128 * 64];
    const int tid = threadIdx.x;
    const int lane = tid & 63, wave = tid >> 6, wm = wave & 1, wn = wave >> 1;
    const int bid = blockIdx.x;
    const int n = bid & 3;
    const int p = bid >> 2;
    int a = 0;
    while ((a + 1) * (a + 2) / 2 <= p) ++a;   // uniform scalar loop, <=16 iters
    const int c = p - a * (a + 1) / 2;
    const int m = a - c;

    floatx4 acc[4][4];
    floatx4 zero = {0.f, 0.f, 0.f, 0.f};
#pragma unroll
    for (int mi = 0; mi < 4; ++mi)
#pragma unroll
        for (int ni = 0; ni < 4; ++ni) acc[mi][ni] = zero;

    const bf16* Ab0 = Tb + (size_t)m * 16384;
    const bf16* Bb0 = YT + (size_t)n * 128 * 2048 + c * 128;
    for (int kv = 0; kv < 48; ++kv) {
        const bf16* Ab = Ab0 + (size_t)kv * 16 * 16384;
        const bf16* Bb = Bb0 + (size_t)kv * 1048576;
#pragma unroll
        for (int kk = 0; kk < 128; kk += 64) {
            stage_tile(Ab + kk, 128, lA, tid);
            stage_tile(Bb + kk, 2048, lB, tid);
            __syncthreads();
            mfma_block(lA, lB, acc, lane, wm, wn);
            __syncthreads();
        }
    }
    float* Pt = P + (size_t)(p * 4 + n) * 16384;
#pragma unroll
    for (int mi = 0; mi < 4; ++mi)
#pragma unroll
        for (int ni = 0; ni < 4; ++ni)
#pragma unroll
            for (int r = 0; r < 4; ++r) {
                int row = wm * 64 + mi * 16 + (lane >> 4) * 4 + r;  // t-local
                int col = wn * 64 + ni * 16 + (lane & 15);          // o-local
                Pt[row * 128 + col] = acc[mi][ni][r];
            }
}

// ---------------------------------------------------------------------------
// AR GEMM: Par[t][o] = sum_{i,d} xar[t][i*512+d] * arWT[o][i*512+d]. K=1536.
// ---------------------------------------------------------------------------
__global__ __launch_bounds__(256) void ar_gemm(const bf16* __restrict__ xar,
                                               const bf16* __restrict__ arWT,
                                               float* __restrict__ Par) {
    __shared__ bf16 lA[128 * 64], lB[128 * 64];
    const int tid = threadIdx.x;
    const int lane = tid & 63, wave = tid >> 6, wm = wave & 1, wn = wave >> 1;
    const int bm = blockIdx.x, bn = blockIdx.y;
    const bf16* Ab = xar + (size_t)bm * 128 * 1536;
    const bf16* Bb = arWT + (size_t)bn * 128 * 1536;

    floatx4 acc[4][4];
    floatx4 zero = {0.f, 0.f, 0.f, 0.f};
#pragma unroll
    for (int mi = 0; mi < 4; ++mi)
#pragma unroll
        for (int ni = 0; ni < 4; ++ni) acc[mi][ni] = zero;

    for (int kk = 0; kk < 1536; kk += 64) {
        stage_tile(Ab + kk, 1536, lA, tid);
        stage_tile(Bb + kk, 1536, lB, tid);
        __syncthreads();
        mfma_block(lA, lB, acc, lane, wm, wn);
        __syncthreads();
    }
#pragma unroll
    for (int mi = 0; mi < 4; ++mi)
#pragma unroll
        for (int ni = 0; ni < 4; ++ni)
#pragma unroll
            for (int r = 0; r < 4; ++r) {
                int t = bm * 128 + wm * 64 + mi * 16 + (lane >> 4) * 4 + r;
                int o = bn * 128 + wn * 64 + ni * 16 + (lane & 15);
                Par[(size_t)t * 512 + o] = acc[mi][ni][r];
            }
}

// ---------------------------------------------------------------------------
// Prep kernels
// ---------------------------------------------------------------------------
__global__ void prep_x(const float* __restrict__ x, bf16* __restrict__ xb,
                       bf16* __restrict__ xar) {
    int idx = blockIdx.x * 256 + threadIdx.x;   // over 2048*512
    if (idx >= 2048 * 512) return;
    int t = idx >> 9, d = idx & 511;
    xb[idx] = (bf16)x[idx];
#pragma unroll
    for (int i = 0; i < 3; ++i) {
        float v = (t - i >= 0) ? x[idx - i * 512] : 0.f;
        xar[(size_t)t * 1536 + i * 512 + d] = (bf16)v;
    }
}

// WbT[(kv*512+o)][d] = Mp/Mm[k][d][o] via 64x64 LDS transpose
__global__ void prep_wbt(const float* __restrict__ Mp, const float* __restrict__ Mm,
                         bf16* __restrict__ WbT) {
    __shared__ float tile[64][65];
    const int kv = blockIdx.x, dt = blockIdx.y * 64, ot = blockIdx.z * 64;
    const float* src = (kv < 24) ? (Mp + (size_t)kv * 262144)
                                 : (Mm + (size_t)(kv - 24) * 262144);
    const int tid = threadIdx.x;
#pragma unroll
    for (int it = 0; it < 16; ++it) {
        int q = it * 256 + tid;
        int r = q >> 6, cc = q & 63;   // r = d-local, cc = o-local
        tile[r][cc] = src[(size_t)(dt + r) * 512 + ot + cc];
    }
    __syncthreads();
#pragma unroll
    for (int it = 0; it < 16; ++it) {
        int q = it * 256 + tid;
        int r = q >> 6, cc = q & 63;   // r = o-local, cc = d-local
        WbT[(size_t)(kv * 512 + ot + r) * 512 + dt + cc] = (bf16)tile[cc][r];
    }
}

// arWT[o][i*512+d] = M[o][d][i]
__global__ void prep_arwt(const float* __restrict__ M, bf16* __restrict__ arWT) {
    __shared__ float row[1536];
    const int o = blockIdx.x, tid = threadIdx.x;
    for (int q = tid; q < 1536; q += 256) row[q] = M[(size_t)o * 1536 + q];
    __syncthreads();
    for (int q = tid; q < 1536; q += 256) {
        int i = q >> 9, d = q & 511;
        arWT[(size_t)o * 1536 + q] = (bf16)row[d * 3 + i];
    }
}

// Tb[kv][m][i][j] = phi_kv[m*128+i-j], phi_alt for kv>=24
__global__ void prep_tb(const float* __restrict__ phi, bf16* __restrict__ Tb) {
    int idx = blockIdx.x * 256 + threadIdx.x;   // over 48*16*128*128
    if (idx >= 48 * 16 * 128 * 128) return;
    int j  = idx & 127;
    int i  = (idx >> 7) & 127;
    int m  = (idx >> 14) & 15;
    int kv = idx >> 18;
    int s  = m * 128 + i - j;                   // always < 2048
    float v = 0.f;
    if (s >= 0) {
        v = phi[s * 24 + (kv >= 24 ? kv - 24 : kv)];
        if (kv >= 24 && (s & 1)) v = -v;
    }
    Tb[idx] = (bf16)v;
}

// out[t][o] = Par[t][o] + sum_{c<=a} P[(tri(a)+c)*4+n][i][ol]
__global__ void reduce_out(const float* __restrict__ P, const float* __restrict__ Par,
                           float* __restrict__ out) {
    int idx = blockIdx.x * 256 + threadIdx.x;   // over 2048*512
    if (idx >= 2048 * 512) return;
    int t = idx >> 9, o = idx & 511;
    int a = t >> 7, i = t & 127, n = o >> 7, ol = o & 127;
    float s = Par[idx];
    int pb = a * (a + 1) / 2;
    for (int c = 0; c <= a; ++c)
        s += P[(size_t)((pb + c) * 4 + n) * 16384 + i * 128 + ol];
    out[idx] = s;
}

// ---------------------------------------------------------------------------
// Launch
// ---------------------------------------------------------------------------
extern "C" void kernel_launch(void* const* d_in, const int* in_sizes, int n_in,
                              void* d_out, int out_size, void* d_ws, size_t ws_size,
                              hipStream_t stream) {
    const float* x   = (const float*)d_in[0];
    const float* phi = (const float*)d_in[1];
    const float* M   = (const float*)d_in[2];
    const float* Mp  = (const float*)d_in[3];
    const float* Mm  = (const float*)d_in[4];
    float* out = (float*)d_out;
    char* ws = (char*)d_ws;

    // workspace layout (bytes)
    bf16*  WbT  = (bf16*)(ws + 0);          //  25,165,824
    bf16*  Tb   = (bf16*)(ws + 25165824);   //  25,165,824
    bf16*  xb   = (bf16*)(ws + 50331648);   //   2,097,152
    bf16*  xar  = (bf16*)(ws + 52428800);   //   6,291,456
    bf16*  arWT = (bf16*)(ws + 58720256);   //   1,572,864
    bf16*  YT   = (bf16*)(ws + 60293120);   // 100,663,296
    float* P    = (float*)(ws + 160956416); //  35,651,584
    float* Par  = (float*)(ws + 196608000); //   4,194,304  (total 200,802,304)

    prep_x<<<4096, 256, 0, stream>>>(x, xb, xar);
    prep_wbt<<<dim3(48, 8, 8), 256, 0, stream>>>(Mp, Mm, WbT);
    prep_arwt<<<512, 256, 0, stream>>>(M, arWT);
    prep_tb<<<49152, 256, 0, stream>>>(phi, Tb);

    yt_gemm<<<dim3(192, 16), 256, 0, stream>>>(WbT, xb, YT);
    conv_gemm<<<544, 256, 0, stream>>>(Tb, YT, P);
    ar_gemm<<<dim3(16, 4), 256, 0, stream>>>(xar, arWT, Par);
    reduce_out<<<4096, 256, 0, stream>>>(P, Par, out);
}

// Round 2
// 394.373 us; speedup vs baseline: 1.1154x; 1.1154x over previous
//
#include <hip/hip_runtime.h>

typedef __bf16 bf16;
typedef bf16 bf16x8 __attribute__((ext_vector_type(8)));
typedef float floatx4 __attribute__((ext_vector_type(4)));

#define AS1 __attribute__((address_space(1)))
#define AS3 __attribute__((address_space(3)))

// ---------------------------------------------------------------------------
// Core tile machinery: 128x128 block, 4 waves (2x2 of 64x64), BK=64,
// 16x16x32 bf16 MFMA. Both operands stored [row][k] (k-contiguous).
// Staging: global_load_lds width=16, lane-contiguous LDS, XOR swizzle applied
// to the GLOBAL column so ds_read_b128 fragment loads are conflict-free.
// LDS[row][c8] = G[row][c8 ^ (row&7)], tile = 128 rows x 64 k (16 KB).
// ---------------------------------------------------------------------------
__device__ __forceinline__ void stage_tile(const bf16* g, int ld, bf16* lds, int tid) {
#pragma unroll
    for (int it = 0; it < 4; ++it) {
        int q    = it * 256 + tid;        // 0..1023, 8 bf16 per q
        int row  = q >> 3;
        int col8 = (q & 7) ^ (row & 7);   // swizzle on global side
        __builtin_amdgcn_global_load_lds(
            (const AS1 void*)(g + (size_t)row * ld + col8 * 8),
            (AS3 void*)(lds + q * 8), 16, 0, 0);
    }
}

__device__ __forceinline__ void mfma_block(const bf16* lA, const bf16* lB,
                                           floatx4 acc[4][4], int lane, int wm, int wn) {
    const int lrow = lane & 15;
    const int lk   = lane >> 4;
#pragma unroll
    for (int s = 0; s < 2; ++s) {   // two K=32 steps per BK=64
        bf16x8 af[4], bfr[4];
        const int c8 = s * 4 + lk;
#pragma unroll
        for (int mi = 0; mi < 4; ++mi) {
            int r = wm * 64 + mi * 16 + lrow;
            af[mi] = *(const bf16x8*)(lA + r * 64 + ((c8 ^ (r & 7)) << 3));
        }
#pragma unroll
        for (int ni = 0; ni < 4; ++ni) {
            int r = wn * 64 + ni * 16 + lrow;
            bfr[ni] = *(const bf16x8*)(lB + r * 64 + ((c8 ^ (r & 7)) << 3));
        }
#pragma unroll
        for (int mi = 0; mi < 4; ++mi)
#pragma unroll
            for (int ni = 0; ni < 4; ++ni)
                acc[mi][ni] = __builtin_amdgcn_mfma_f32_16x16x32_bf16(
                    af[mi], bfr[ni], acc[mi][ni], 0, 0, 0);
    }
}

// ---------------------------------------------------------------------------
// GEMM1: YT[kv*512+o][t] = sum_d WbT[kv*512+o][d] * xb[t][d]
// ---------------------------------------------------------------------------
__global__ __launch_bounds__(256) void yt_gemm(const bf16* __restrict__ WbT,
                                               const bf16* __restrict__ xb,
                                               bf16* __restrict__ YT) {
    __shared__ bf16 lA[128 * 64], lB[128 * 64];
    const int tid = threadIdx.x;
    const int lane = tid & 63, wave = tid >> 6, wm = wave & 1, wn = wave >> 1;
    const int bm = blockIdx.x, bn = blockIdx.y;
    const bf16* Ab = WbT + (size_t)bm * 128 * 512;
    const bf16* Bb = xb + (size_t)bn * 128 * 512;

    floatx4 acc[4][4];
    floatx4 zero = {0.f, 0.f, 0.f, 0.f};
#pragma unroll
    for (int mi = 0; mi < 4; ++mi)
#pragma unroll
        for (int ni = 0; ni < 4; ++ni) acc[mi][ni] = zero;

    for (int kk = 0; kk < 512; kk += 64) {
        stage_tile(Ab + kk, 512, lA, tid);
        stage_tile(Bb + kk, 512, lB, tid);
        __syncthreads();
        mfma_block(lA, lB, acc, lane, wm, wn);
        __syncthreads();
    }
#pragma unroll
    for (int mi = 0; mi < 4; ++mi)
#pragma unroll
        for (int ni = 0; ni < 4; ++ni)
#pragma unroll
            for (int r = 0; r < 4; ++r) {
                int ko = bm * 128 + wm * 64 + mi * 16 + (lane >> 4) * 4 + r;
                int t  = bn * 128 + wn * 64 + ni * 16 + (lane & 15);
                YT[(size_t)ko * 2048 + t] = (bf16)acc[mi][ni][r];
            }
}

// ---------------------------------------------------------------------------
// conv GEMM, kv-split by 2: one block per (p=(a,c), n, s). Grid 1088 (all
// resident: 32KB LDS -> 5 blocks/CU cap, 96 VGPR -> 5 waves/SIMD cap).
// K = 24 kv slices x 128. Partials to packed P tile [(p*4+n)*2+s].
// ---------------------------------------------------------------------------
__global__ __launch_bounds__(256) void conv_gemm(const bf16* __restrict__ Tb,
                                                 const bf16* __restrict__ YT,
                                                 float* __restrict__ P) {
    __shared__ bf16 lA[128 * 64], lB[128 * 64];
    const int tid = threadIdx.x;
    const int lane = tid & 63, wave = tid >> 6, wm = wave & 1, wn = wave >> 1;
    const int bid = blockIdx.x;
    const int s  = bid & 1;
    const int n  = (bid >> 1) & 3;
    const int p  = bid >> 3;
    int a = 0;
    while ((a + 1) * (a + 2) / 2 <= p) ++a;   // uniform scalar loop, <=16 iters
    const int c = p - a * (a + 1) / 2;
    const int m = a - c;

    floatx4 acc[4][4];
    floatx4 zero = {0.f, 0.f, 0.f, 0.f};
#pragma unroll
    for (int mi = 0; mi < 4; ++mi)
#pragma unroll
        for (int ni = 0; ni < 4; ++ni) acc[mi][ni] = zero;

    const bf16* Ab0 = Tb + (size_t)m * 16384;
    const bf16* Bb0 = YT + (size_t)n * 128 * 2048 + c * 128;
    for (int kv = s * 24; kv < s * 24 + 24; ++kv) {
        const bf16* Ab = Ab0 + (size_t)kv * 16 * 16384;
        const bf16* Bb = Bb0 + (size_t)kv * 1048576;
#pragma unroll
        for (int kk = 0; kk < 128; kk += 64) {
            stage_tile(Ab + kk, 128, lA, tid);
            stage_tile(Bb + kk, 2048, lB, tid);
            __syncthreads();
            mfma_block(lA, lB, acc, lane, wm, wn);
            __syncthreads();
        }
    }
    float* Pt = P + (size_t)((p * 4 + n) * 2 + s) * 16384;
#pragma unroll
    for (int mi = 0; mi < 4; ++mi)
#pragma unroll
        for (int ni = 0; ni < 4; ++ni)
#pragma unroll
            for (int r = 0; r < 4; ++r) {
                int row = wm * 64 + mi * 16 + (lane >> 4) * 4 + r;  // t-local
                int col = wn * 64 + ni * 16 + (lane & 15);          // o-local
                Pt[row * 128 + col] = acc[mi][ni][r];
            }
}

// ---------------------------------------------------------------------------
// AR GEMM: Par[t][o] = sum_{i,d} xar[t][i*512+d] * arWT[o][i*512+d]. K=1536.
// ---------------------------------------------------------------------------
__global__ __launch_bounds__(256) void ar_gemm(const bf16* __restrict__ xar,
                                               const bf16* __restrict__ arWT,
                                               float* __restrict__ Par) {
    __shared__ bf16 lA[128 * 64], lB[128 * 64];
    const int tid = threadIdx.x;
    const int lane = tid & 63, wave = tid >> 6, wm = wave & 1, wn = wave >> 1;
    const int bm = blockIdx.x, bn = blockIdx.y;
    const bf16* Ab = xar + (size_t)bm * 128 * 1536;
    const bf16* Bb = arWT + (size_t)bn * 128 * 1536;

    floatx4 acc[4][4];
    floatx4 zero = {0.f, 0.f, 0.f, 0.f};
#pragma unroll
    for (int mi = 0; mi < 4; ++mi)
#pragma unroll
        for (int ni = 0; ni < 4; ++ni) acc[mi][ni] = zero;

    for (int kk = 0; kk < 1536; kk += 64) {
        stage_tile(Ab + kk, 1536, lA, tid);
        stage_tile(Bb + kk, 1536, lB, tid);
        __syncthreads();
        mfma_block(lA, lB, acc, lane, wm, wn);
        __syncthreads();
    }
#pragma unroll
    for (int mi = 0; mi < 4; ++mi)
#pragma unroll
        for (int ni = 0; ni < 4; ++ni)
#pragma unroll
            for (int r = 0; r < 4; ++r) {
                int t = bm * 128 + wm * 64 + mi * 16 + (lane >> 4) * 4 + r;
                int o = bn * 128 + wn * 64 + ni * 16 + (lane & 15);
                Par[(size_t)t * 512 + o] = acc[mi][ni][r];
            }
}

// ---------------------------------------------------------------------------
// Fused prep: block ranges dispatch prep_x / prep_wbt / prep_arwt / prep_tb
// ---------------------------------------------------------------------------
__global__ void prep_all(const float* __restrict__ x, const float* __restrict__ phi,
                         const float* __restrict__ M, const float* __restrict__ Mp,
                         const float* __restrict__ Mm, bf16* __restrict__ xb,
                         bf16* __restrict__ xar, bf16* __restrict__ WbT,
                         bf16* __restrict__ arWT, bf16* __restrict__ Tb) {
    __shared__ float smem[64 * 65];
    const int b = blockIdx.x, tid = threadIdx.x;
    if (b < 4096) {
        // prep_x over 2048*512
        int idx = b * 256 + tid;
        int t = idx >> 9;
        xb[idx] = (bf16)x[idx];
#pragma unroll
        for (int i = 0; i < 3; ++i) {
            float v = (t - i >= 0) ? x[idx - i * 512] : 0.f;
            xar[(size_t)(idx & ~511) * 3 + i * 512 + (idx & 511)] = (bf16)v;
        }
    } else if (b < 7168) {
        // prep_wbt: WbT[(kv*512+o)][d] = Mp/Mm[k][d][o] via 64x64 LDS transpose
        int b2 = b - 4096;
        int kv = b2 >> 6, rem = b2 & 63;
        int dt = (rem >> 3) * 64, ot = (rem & 7) * 64;
        const float* src = (kv < 24) ? (Mp + (size_t)kv * 262144)
                                     : (Mm + (size_t)(kv - 24) * 262144);
#pragma unroll
        for (int it = 0; it < 16; ++it) {
            int q = it * 256 + tid;
            int r = q >> 6, cc = q & 63;
            smem[r * 65 + cc] = src[(size_t)(dt + r) * 512 + ot + cc];
        }
        __syncthreads();
#pragma unroll
        for (int it = 0; it < 16; ++it) {
            int q = it * 256 + tid;
            int r = q >> 6, cc = q & 63;
            WbT[(size_t)(kv * 512 + ot + r) * 512 + dt + cc] = (bf16)smem[cc * 65 + r];
        }
    } else if (b < 7680) {
        // prep_arwt: arWT[o][i*512+d] = M[o][d][i]
        int o = b - 7168;
        for (int q = tid; q < 1536; q += 256) smem[q] = M[(size_t)o * 1536 + q];
        __syncthreads();
        for (int q = tid; q < 1536; q += 256) {
            int i = q >> 9, d = q & 511;
            arWT[(size_t)o * 1536 + q] = (bf16)smem[d * 3 + i];
        }
    } else {
        // prep_tb: Tb[kv][m][i][j] = phi_kv[m*128+i-j], alt-sign for kv>=24
        int idx = (b - 7680) * 256 + tid;   // over 48*16*128*128
        int j  = idx & 127;
        int i  = (idx >> 7) & 127;
        int m  = (idx >> 14) & 15;
        int kv = idx >> 18;
        int sh = m * 128 + i - j;
        float v = 0.f;
        if (sh >= 0) {
            v = phi[sh * 24 + (kv >= 24 ? kv - 24 : kv)];
            if (kv >= 24 && (sh & 1)) v = -v;
        }
        Tb[idx] = (bf16)v;
    }
}

// out[t][o] = Par[t][o] + sum_{c<=a, s<2} P[((tri(a)+c)*4+n)*2+s][i][ol]
__global__ void reduce_out(const float* __restrict__ P, const float* __restrict__ Par,
                           float* __restrict__ out) {
    int idx = blockIdx.x * 256 + threadIdx.x;   // over 2048*512
    if (idx >= 2048 * 512) return;
    int t = idx >> 9, o = idx & 511;
    int a = t >> 7, i = t & 127, n = o >> 7, ol = o & 127;
    float s = Par[idx];
    int pb = a * (a + 1) / 2;
    for (int c = 0; c <= a; ++c) {
        size_t base = (size_t)((pb + c) * 4 + n) * 2 * 16384 + i * 128 + ol;
        s += P[base] + P[base + 16384];
    }
    out[idx] = s;
}

// ---------------------------------------------------------------------------
// Launch
// ---------------------------------------------------------------------------
extern "C" void kernel_launch(void* const* d_in, const int* in_sizes, int n_in,
                              void* d_out, int out_size, void* d_ws, size_t ws_size,
                              hipStream_t stream) {
    const float* x   = (const float*)d_in[0];
    const float* phi = (const float*)d_in[1];
    const float* M   = (const float*)d_in[2];
    const float* Mp  = (const float*)d_in[3];
    const float* Mm  = (const float*)d_in[4];
    float* out = (float*)d_out;
    char* ws = (char*)d_ws;

    // workspace layout (bytes)
    bf16*  WbT  = (bf16*)(ws + 0);          //  25,165,824
    bf16*  Tb   = (bf16*)(ws + 25165824);   //  25,165,824
    bf16*  xb   = (bf16*)(ws + 50331648);   //   2,097,152
    bf16*  xar  = (bf16*)(ws + 52428800);   //   6,291,456
    bf16*  arWT = (bf16*)(ws + 58720256);   //   1,572,864
    bf16*  YT   = (bf16*)(ws + 60293120);   // 100,663,296
    float* P    = (float*)(ws + 160956416); //  71,303,168 (544 tiles x 2 splits)
    float* Par  = (float*)(ws + 232259584); //   4,194,304  (total 236,453,888)

    prep_all<<<56832, 256, 0, stream>>>(x, phi, M, Mp, Mm, xb, xar, WbT, arWT, Tb);
    yt_gemm<<<dim3(192, 16), 256, 0, stream>>>(WbT, xb, YT);
    conv_gemm<<<1088, 256, 0, stream>>>(Tb, YT, P);
    ar_gemm<<<dim3(16, 4), 256, 0, stream>>>(xar, arWT, Par);
    reduce_out<<<4096, 256, 0, stream>>>(P, Par, out);
}